// Round 7
// baseline (211.887 us; speedup 1.0000x reference)
//
#include <hip/hip_runtime.h>
#include <stdint.h>

#define B_   8
#define KB_  16
#define SEQ_ 512
#define HID_ 768

#define NKB  (HID_ / 32)         // 24 k-blocks (32 halves each) per row
#define QRB  (B_  * SEQ_ / 16)   // 256 Q row-blocks of 16 rows
#define KRB  (KB_ * SEQ_ / 16)   // 512 K row-blocks

typedef __attribute__((ext_vector_type(4))) _Float16 half4;
typedef __attribute__((ext_vector_type(8))) _Float16 half8;
typedef __attribute__((ext_vector_type(4))) float    floatx4;

#define GLOBAL_AS __attribute__((address_space(1)))
#define LDS_AS    __attribute__((address_space(3)))

// Band-elision: for |s-t| >= 193 and alpha >= 18/193, w = expf(-alpha*d) <= 1.6e-8,
// so expf(cv*w) == 1.0f exactly (|cv*w| < 2^-25). Those GEMM tiles are skipped in
// li_part (acc=0 -> ps contribution exact, ns contribution 0) and ns is restored in
// li_reduce via the rank-1 identity sum_far kmv*cv = qn[s] . (sum_far kmv*kn[t]).
// ktile accumulates the SAME fp16-rounded kn values the MFMA consumes, so the
// correction matches the replaced MFMA terms to accumulation-order error.
#define SKIP_OK(alpha) ((alpha) * 193.f >= 18.f)

// workspace: Qt + Kt + Pbuf (rounds 0-5 layout) + ktile (new, gated on ws_size)
#define WS_BASE  ((size_t)(B_ + KB_) * SEQ_ * HID_ * 2 + (size_t)B_ * KB_ * SEQ_ * 4 * sizeof(float))
#define WS_KTILE ((size_t)KB_ * 32 * 768 * sizeof(float))

// async 16B/lane global->LDS copy: LDS dest = base + lane*16 (wave-uniform base)
static __device__ __forceinline__ void async_tile16(const _Float16* g, _Float16* l)
{
    __builtin_amdgcn_global_load_lds((const GLOBAL_AS uint32_t*)g,
                                     (LDS_AS uint32_t*)l, 16, 0, 0);
}

// ---------------- prepass: L2-normalize rows -> fp16 in MFMA-fragment-tiled layout ----
// Tile = 16 rows x 32 k = 1KB, lane-major: element(row,k) at lane = row | ((k>>3)<<4),
// idx = k&7. One 256-thread block per 16-row block. If elide: K-blocks additionally
// emit ktile[j][tb16][768] = sum over the tile's 16 rows of kmask * fp16(kn) (fp32).
#define LP 776   // LDS row stride in halves

__global__ __launch_bounds__(256)
void prep_tile(const float* __restrict__ Q, const float* __restrict__ K,
               const int* __restrict__ kmask,
               _Float16* __restrict__ Qt, _Float16* __restrict__ Kt,
               float* __restrict__ ktile, int elide)
{
    const int rb = blockIdx.x;   // 0..767
    const bool isK = (rb >= QRB);
    const float* src;
    _Float16*    dst;
    if (!isK) { src = Q + (size_t)rb * 16 * HID_;          dst = Qt + (size_t)rb * NKB * 512; }
    else      { src = K + (size_t)(rb - QRB) * 16 * HID_;  dst = Kt + (size_t)(rb - QRB) * NKB * 512; }
    const int rbk  = rb - QRB;        // K rowblock index (valid if isK)
    const int jj   = rbk >> 5;        // j
    const int tb16 = rbk & 31;        // t-tile within row

    __shared__ _Float16 Ls[16 * LP];
    __shared__ float Kred[4 * 768];
    const int wave = threadIdx.x >> 6;
    const int lane = threadIdx.x & 63;
    const bool doK = isK && (elide != 0);

    float4 ka[3];
#pragma unroll
    for (int it = 0; it < 3; ++it) ka[it] = (float4){0.f, 0.f, 0.f, 0.f};

#pragma unroll
    for (int rr = 0; rr < 4; ++rr) {
        int row = wave * 4 + rr;
        const float* s = src + (size_t)row * HID_;
        float4 v[3];
        float ss = 0.f;
#pragma unroll
        for (int it = 0; it < 3; ++it) {
            v[it] = *(const float4*)(s + lane * 4 + it * 256);
            ss += v[it].x * v[it].x + v[it].y * v[it].y + v[it].z * v[it].z + v[it].w * v[it].w;
        }
#pragma unroll
        for (int m = 1; m < 64; m <<= 1) ss += __shfl_xor(ss, m, 64);
        float sc = 1.0f / fmaxf(sqrtf(ss), 1e-12f);
#pragma unroll
        for (int it = 0; it < 3; ++it) {
            half4 h = { (_Float16)(v[it].x * sc), (_Float16)(v[it].y * sc),
                        (_Float16)(v[it].z * sc), (_Float16)(v[it].w * sc) };
            *(half4*)(Ls + row * LP + lane * 4 + it * 256) = h;
            if (doK) {
                // accumulate from the fp16-ROUNDED values (what the MFMA sees)
                int kmv = kmask[jj * SEQ_ + tb16 * 16 + row];
                if (kmv) {
                    ka[it].x += (float)h.x; ka[it].y += (float)h.y;
                    ka[it].z += (float)h.z; ka[it].w += (float)h.w;
                }
            }
        }
    }
    if (doK) {
#pragma unroll
        for (int it = 0; it < 3; ++it)
            *(float4*)(Kred + wave * 768 + lane * 4 + it * 256) = ka[it];
    }
    __syncthreads();

#pragma unroll
    for (int rep = 0; rep < 6; ++rep) {
        int slot = rep * 256 + threadIdx.x;      // 0..1535 = 24 tiles x 64 lanes
        int kb   = slot >> 6;
        int ln   = slot & 63;
        int row  = ln & 15;
        int ko   = kb * 32 + (ln >> 4) * 8;
        half8 h = *(const half8*)(Ls + row * LP + ko);
        *(half8*)(dst + (size_t)kb * 512 + (size_t)ln * 8) = h;
    }

    if (doK && threadIdx.x < 192) {
        int h = threadIdx.x * 4;
        float4 s0 = *(const float4*)(Kred + h);
        float4 s1 = *(const float4*)(Kred + 768 + h);
        float4 s2 = *(const float4*)(Kred + 1536 + h);
        float4 s3 = *(const float4*)(Kred + 2304 + h);
        float4 r = { s0.x + s1.x + s2.x + s3.x, s0.y + s1.y + s2.y + s3.y,
                     s0.z + s1.z + s2.z + s3.z, s0.w + s1.w + s2.w + s3.w };
        *(float4*)(ktile + ((size_t)jj * 32 + tb16) * 768 + h) = r;
    }
}

// ---------------- phase 1: LDS-staged GEMM (128x256 tile) + sum-softmax partials ------
// grid: x = st*2 + tb (8), y = j (16), z = i (8); 512 threads = 8 waves of 64x64.
// Identical to the proven baseline EXCEPT (when elide): waves whose 64x64 output block
// is entirely in the far band (|sB - tB| >= 4, min |s-t| = 193) skip their frag reads
// + MFMAs (acc stays 0), and K-tiles needed by no resident wave are not staged.
__global__ __launch_bounds__(512, 4)
void li_part(const _Float16* __restrict__ Qt, const _Float16* __restrict__ Kt,
             const float* __restrict__ alpha_p, const int* __restrict__ kmask,
             float* __restrict__ Pbuf, int elide)
{
    const int st = blockIdx.x >> 1;   // s tile (0..3), 128 rows
    const int tb = blockIdx.x & 1;    // t half (0..1), 256 cols
    const int j  = blockIdx.y;
    const int i  = blockIdx.z;

    const int tid  = threadIdx.x;
    const int lane = tid & 63;
    const int wave = tid >> 6;        // 0..7
    const int quad = lane >> 4;
    const int l16  = lane & 15;
    const int wr   = wave >> 2;       // row half (0/1): rows wr*64..+63
    const int wc   = wave & 3;        // col quarter (0..3): cols wc*64..+63

    // double-buffered staging: 24 tiles (8 Q + 16 K) x 512 halves per buffer
    __shared__ _Float16 Sbuf[2][24 * 512];
    __shared__ float lred[4][128], nred[4][128];

    const float araw  = *alpha_p;
    const float alpha = araw >= 0.f ? araw : 0.01f * araw;   // leaky_relu
    const bool skip_en = (elide != 0) && SKIP_OK(alpha);

    // this wave's 64-row / 64-col block position in 64-units
    const int sB = st * 2 + wr;       // 0..7
    const int tB = tb * 4 + wc;       // 0..7
    const int dB = sB - tB;
    const bool wskip = skip_en && (dB >= 4 || dB <= -4);

    const int qbase = i * 32 + st * 8;        // Q row-block index
    const int kbase = j * 32 + tb * 16;       // K row-block index

    // staging assignment: this wave stages tiles wave*3 .. wave*3+2
    const _Float16* gsrc[3];
    _Float16*       ldst0[3];
    bool            need[3];
#pragma unroll
    for (int q = 0; q < 3; ++q) {
        int t   = wave * 3 + q;
        int rbg = (t < 8) ? (qbase + t) : (kbase + (t - 8));
        const _Float16* base = (t < 8) ? Qt : Kt;
        gsrc[q]  = base + (size_t)rbg * NKB * 512 + (size_t)lane * 8;
        ldst0[q] = &Sbuf[0][t * 512];
        if (t < 8) need[q] = true;
        else {
            int tBq = tb * 4 + ((t - 8) >> 2);
            int d0 = st * 2 - tBq, d1 = st * 2 + 1 - tBq;
            bool near = (d0 <= 3 && d0 >= -3) || (d1 <= 3 && d1 >= -3);
            need[q] = !skip_en || near;
        }
    }

    floatx4 acc[4][4];
#pragma unroll
    for (int rt = 0; rt < 4; ++rt)
#pragma unroll
        for (int ct = 0; ct < 4; ++ct)
            acc[rt][ct] = (floatx4){0.f, 0.f, 0.f, 0.f};

    // stage kb=0 into buffer 0
#pragma unroll
    for (int q = 0; q < 3; ++q)
        if (need[q]) async_tile16(gsrc[q], ldst0[q]);

    for (int kb = 0; kb < NKB; ++kb) {
        const int b = kb & 1;
        __syncthreads();   // drains own staging (vmcnt) + fences prior reads of buf b^1
        if (kb + 1 < NKB) {
#pragma unroll
            for (int q = 0; q < 3; ++q)
                if (need[q]) async_tile16(gsrc[q] + (size_t)(kb + 1) * 512, ldst0[q] + (b ^ 1) * 24 * 512);
        }
        if (!wskip) {
            const _Float16* Qs = &Sbuf[b][0];
            const _Float16* Ks = &Sbuf[b][8 * 512];
            half8 af[4], bf[4];
#pragma unroll
            for (int rt = 0; rt < 4; ++rt)
                af[rt] = *(const half8*)(Qs + (wr * 4 + rt) * 512 + lane * 8);
#pragma unroll
            for (int ct = 0; ct < 4; ++ct)
                bf[ct] = *(const half8*)(Ks + (wc * 4 + ct) * 512 + lane * 8);
#pragma unroll
            for (int rt = 0; rt < 4; ++rt)
#pragma unroll
                for (int ct = 0; ct < 4; ++ct)
                    acc[rt][ct] = __builtin_amdgcn_mfma_f32_16x16x32_f16(af[rt], bf[ct], acc[rt][ct], 0, 0, 0);
        }
    }

    // ---- epilogue: sum-softmax partials (logits in [-1,1] -> no max needed) ----
    // For skipped waves acc==0: e = kmv ? expf(0) = 1 : 0 -> ps exact, ns contributes 0
    // (restored in li_reduce via the rank-1 far correction).
    const int* km = kmask + j * SEQ_ + tb * 256;
    int kmv[4]; float tgf[4];
#pragma unroll
    for (int ct = 0; ct < 4; ++ct) {
        int t_loc = wc * 64 + ct * 16 + l16;
        kmv[ct] = km[t_loc];
        tgf[ct] = (float)(tb * 256 + t_loc);
    }
#pragma unroll
    for (int rt = 0; rt < 4; ++rt) {
#pragma unroll
        for (int r = 0; r < 4; ++r) {
            float sgf = (float)(st * 128 + wr * 64 + rt * 16 + quad * 4 + r);
            float ps = 0.f, ns = 0.f;
#pragma unroll
            for (int ct = 0; ct < 4; ++ct) {
                float cv = acc[rt][ct][r];
                float e  = kmv[ct] ? __expf(cv * __expf(-alpha * fabsf(sgf - tgf[ct]))) : 0.f;
                ps += e;
                ns += e * cv;
            }
#pragma unroll
            for (int msk = 1; msk < 16; msk <<= 1) {
                ps += __shfl_xor(ps, msk, 64);
                ns += __shfl_xor(ns, msk, 64);
            }
            if (l16 == 0) {
                int rloc = wr * 64 + rt * 16 + quad * 4 + r;
                lred[wc][rloc] = ps;
                nred[wc][rloc] = ns;
            }
        }
    }
    __syncthreads();

    // merge 4 col-quarters; one (l,n) per row per t-half
    if (tid < 128) {
        float l = lred[0][tid] + lred[1][tid] + lred[2][tid] + lred[3][tid];
        float n = nred[0][tid] + nred[1][tid] + nred[2][tid] + nred[3][tid];
        size_t base = (((size_t)(i * KB_ + j) * SEQ_) + st * 128 + tid) * 4 + tb * 2;
        Pbuf[base]     = l;
        Pbuf[base + 1] = n;
    }
}

// ---------------- phase 2: far correction + merge t-halves + reduce over s ------------
// nfar[s] = qn[s] . sum_{tb16: |(tb16>>2) - (s>>6)| >= 4} ktile[j][tb16][:]
// score(s) = (n_near + nfar) / l, masked by q_mask, summed over s.
__global__ __launch_bounds__(256)
void li_reduce(const float* __restrict__ Pbuf, const int* __restrict__ qmask,
               const _Float16* __restrict__ Qt, const float* __restrict__ ktile,
               const float* __restrict__ alpha_p, float* __restrict__ out, int elide)
{
    const int ij = blockIdx.x;
    const int i  = ij >> 4;           // KB_ == 16
    const int j  = ij & 15;
    const int tid  = threadIdx.x;
    const int lane = tid & 63;
    const int wave = tid >> 6;

    __shared__ float wv[768];
    __shared__ float nfar[512];
    __shared__ float red[4];

    const float araw  = *alpha_p;
    const float alpha = araw >= 0.f ? araw : 0.01f * araw;   // leaky_relu
    const bool skip_en = (elide != 0) && SKIP_OK(alpha);

    if (skip_en) {
        const int h0 = tid * 3;   // 256 * 3 = 768
        const float* kt = ktile + (size_t)j * 32 * 768;
        for (int sB = 0; sB < 8; ++sB) {
            float a0 = 0.f, a1 = 0.f, a2 = 0.f;
            for (int t16 = 0; t16 < 32; ++t16) {
                int d = (t16 >> 2) - sB;
                if (d >= 4 || d <= -4) {
                    const float* p = kt + t16 * 768 + h0;
                    a0 += p[0]; a1 += p[1]; a2 += p[2];
                }
            }
            wv[h0] = a0; wv[h0 + 1] = a1; wv[h0 + 2] = a2;
            __syncthreads();
            // wave handles Q rowblock i*32 + sB*4 + wave (16 s-rows).
            // Qt tile layout: element(row,k) at lane = row|((k>>3)<<4), idx = k&7.
            const _Float16* qb = Qt + ((size_t)i * 32 + sB * 4 + wave) * (NKB * 512)
                                    + (size_t)lane * 8;
            const int kq = (lane >> 4) * 8;
            float p = 0.f;
            for (int kb = 0; kb < NKB; ++kb) {
                half8 q8 = *(const half8*)(qb + kb * 512);
                const float* w8 = wv + kb * 32 + kq;
#pragma unroll
                for (int m = 0; m < 8; ++m) p += (float)q8[m] * w8[m];
            }
            p += __shfl_xor(p, 16, 64);   // sum the 4 lanes sharing a row
            p += __shfl_xor(p, 32, 64);
            if (lane < 16) nfar[sB * 64 + wave * 16 + lane] = p;
            __syncthreads();
        }
    } else {
        nfar[tid] = 0.f; nfar[tid + 256] = 0.f;
        __syncthreads();
    }

    float sum = 0.f;
#pragma unroll
    for (int rep = 0; rep < 2; ++rep) {
        int s = tid + rep * 256;
        float4 a = *(const float4*)(Pbuf + ((size_t)ij * SEQ_ + s) * 4);
        float l = a.x + a.z;
        float n = a.y + a.w + nfar[s];
        float sc = (l > 0.f) ? n / l : 0.f;
        if (qmask[i * SEQ_ + s] == 0) sc = 0.f;
        sum += sc;
    }
#pragma unroll
    for (int m = 1; m < 64; m <<= 1) sum += __shfl_xor(sum, m, 64);
    if ((tid & 63) == 0) red[tid >> 6] = sum;
    __syncthreads();
    if (tid == 0) out[ij] = red[0] + red[1] + red[2] + red[3];
}

extern "C" void kernel_launch(void* const* d_in, const int* in_sizes, int n_in,
                              void* d_out, int out_size, void* d_ws, size_t ws_size,
                              hipStream_t stream)
{
    const float* Q       = (const float*)d_in[0];
    const float* K       = (const float*)d_in[1];
    const float* alpha_p = (const float*)d_in[2];
    const int*   qmask   = (const int*)d_in[3];
    const int*   kmask   = (const int*)d_in[4];
    float*       out     = (float*)d_out;

    char* ws = (char*)d_ws;
    _Float16* Qt    = (_Float16*)ws;
    _Float16* Kt    = (_Float16*)(ws + (size_t)B_ * SEQ_ * HID_ * 2);
    float*    Pbuf  = (float*)   (ws + (size_t)(B_ + KB_) * SEQ_ * HID_ * 2);
    float*    ktile = (float*)   (ws + WS_BASE);

    // band-elision needs +1.5 MB workspace past the baseline layout; gate on ws_size
    const int elide = (ws_size >= WS_BASE + WS_KTILE) ? 1 : 0;

    prep_tile<<<QRB + KRB, 256, 0, stream>>>(Q, K, kmask, Qt, Kt, ktile, elide);

    dim3 grid(8, KB_, B_);   // (st*2+tb, j, i)
    li_part<<<grid, 512, 0, stream>>>(Qt, Kt, alpha_p, kmask, Pbuf, elide);

    li_reduce<<<B_ * KB_, 256, 0, stream>>>(Pbuf, qmask, Qt, ktile, alpha_p, out, elide);
}

// Round 8
// 170.086 us; speedup vs baseline: 1.2458x; 1.2458x over previous
//
#include <hip/hip_runtime.h>
#include <stdint.h>

#define B_   8
#define KB_  16
#define SEQ_ 512
#define HID_ 768

#define NKB  (HID_ / 32)         // 24 k-blocks (32 halves each) per row
#define QRB  (B_  * SEQ_ / 16)   // 256 Q row-blocks of 16 rows
#define KRB  (KB_ * SEQ_ / 16)   // 512 K row-blocks

typedef __attribute__((ext_vector_type(4))) _Float16 half4;
typedef __attribute__((ext_vector_type(8))) _Float16 half8;
typedef __attribute__((ext_vector_type(4))) float    floatx4;

#define GLOBAL_AS __attribute__((address_space(1)))
#define LDS_AS    __attribute__((address_space(3)))

// Band-elision: for |s-t| >= 193 and alpha >= 18/193, w = expf(-alpha*d) <= 1.6e-8,
// so expf(cv*w) == 1.0f exactly (|cv*w| < 2^-25). Those GEMM tiles are skipped in
// li_part (acc=0 -> ps contribution exact, ns contribution 0) and ns is restored in
// li_reduce via the rank-1 identity sum_far kmv*cv = qn[s] . (sum_far kmv*kn[t]).
// ktile accumulates the SAME fp16-rounded kn values the MFMA consumes.
#define SKIP_OK(alpha) ((alpha) * 193.f >= 18.f)

// workspace: Qt + Kt + Pbuf (rounds 0-5 layout) + ktile (gated on ws_size)
#define WS_BASE  ((size_t)(B_ + KB_) * SEQ_ * HID_ * 2 + (size_t)B_ * KB_ * SEQ_ * 4 * sizeof(float))
#define WS_KTILE ((size_t)KB_ * 32 * 768 * sizeof(float))

// async 16B/lane global->LDS copy: LDS dest = base + lane*16 (wave-uniform base)
static __device__ __forceinline__ void async_tile16(const _Float16* g, _Float16* l)
{
    __builtin_amdgcn_global_load_lds((const GLOBAL_AS uint32_t*)g,
                                     (LDS_AS uint32_t*)l, 16, 0, 0);
}

// ---------------- prepass: L2-normalize rows -> fp16 in MFMA-fragment-tiled layout ----
// Tile = 16 rows x 32 k = 1KB, lane-major: element(row,k) at lane = row | ((k>>3)<<4),
// idx = k&7. One 256-thread block per 16-row block. If elide: K-blocks additionally
// emit ktile[j][tb16][768] = sum over the tile's 16 rows of kmask * fp16(kn) (fp32).
#define LP 776   // LDS row stride in halves

__global__ __launch_bounds__(256)
void prep_tile(const float* __restrict__ Q, const float* __restrict__ K,
               const int* __restrict__ kmask,
               _Float16* __restrict__ Qt, _Float16* __restrict__ Kt,
               float* __restrict__ ktile, int elide)
{
    const int rb = blockIdx.x;   // 0..767
    const bool isK = (rb >= QRB);
    const float* src;
    _Float16*    dst;
    if (!isK) { src = Q + (size_t)rb * 16 * HID_;          dst = Qt + (size_t)rb * NKB * 512; }
    else      { src = K + (size_t)(rb - QRB) * 16 * HID_;  dst = Kt + (size_t)(rb - QRB) * NKB * 512; }
    const int rbk  = rb - QRB;        // K rowblock index (valid if isK)
    const int jj   = rbk >> 5;        // j
    const int tb16 = rbk & 31;        // t-tile within row

    __shared__ _Float16 Ls[16 * LP];
    __shared__ float Kred[4 * 768];
    const int wave = threadIdx.x >> 6;
    const int lane = threadIdx.x & 63;
    const bool doK = isK && (elide != 0);

    float4 ka[3];
#pragma unroll
    for (int it = 0; it < 3; ++it) ka[it] = (float4){0.f, 0.f, 0.f, 0.f};

#pragma unroll
    for (int rr = 0; rr < 4; ++rr) {
        int row = wave * 4 + rr;
        const float* s = src + (size_t)row * HID_;
        float4 v[3];
        float ss = 0.f;
#pragma unroll
        for (int it = 0; it < 3; ++it) {
            v[it] = *(const float4*)(s + lane * 4 + it * 256);
            ss += v[it].x * v[it].x + v[it].y * v[it].y + v[it].z * v[it].z + v[it].w * v[it].w;
        }
#pragma unroll
        for (int m = 1; m < 64; m <<= 1) ss += __shfl_xor(ss, m, 64);
        float sc = 1.0f / fmaxf(sqrtf(ss), 1e-12f);
#pragma unroll
        for (int it = 0; it < 3; ++it) {
            half4 h = { (_Float16)(v[it].x * sc), (_Float16)(v[it].y * sc),
                        (_Float16)(v[it].z * sc), (_Float16)(v[it].w * sc) };
            *(half4*)(Ls + row * LP + lane * 4 + it * 256) = h;
            if (doK) {
                // accumulate from the fp16-ROUNDED values (what the MFMA sees)
                int kmv = kmask[jj * SEQ_ + tb16 * 16 + row];
                if (kmv) {
                    ka[it].x += (float)h.x; ka[it].y += (float)h.y;
                    ka[it].z += (float)h.z; ka[it].w += (float)h.w;
                }
            }
        }
    }
    if (doK) {
#pragma unroll
        for (int it = 0; it < 3; ++it)
            *(float4*)(Kred + wave * 768 + lane * 4 + it * 256) = ka[it];
    }
    __syncthreads();

#pragma unroll
    for (int rep = 0; rep < 6; ++rep) {
        int slot = rep * 256 + threadIdx.x;      // 0..1535 = 24 tiles x 64 lanes
        int kb   = slot >> 6;
        int ln   = slot & 63;
        int row  = ln & 15;
        int ko   = kb * 32 + (ln >> 4) * 8;
        half8 h = *(const half8*)(Ls + row * LP + ko);
        *(half8*)(dst + (size_t)kb * 512 + (size_t)ln * 8) = h;
    }

    if (doK && threadIdx.x < 192) {
        int h = threadIdx.x * 4;
        float4 s0 = *(const float4*)(Kred + h);
        float4 s1 = *(const float4*)(Kred + 768 + h);
        float4 s2 = *(const float4*)(Kred + 1536 + h);
        float4 s3 = *(const float4*)(Kred + 2304 + h);
        float4 r = { s0.x + s1.x + s2.x + s3.x, s0.y + s1.y + s2.y + s3.y,
                     s0.z + s1.z + s2.z + s3.z, s0.w + s1.w + s2.w + s3.w };
        *(float4*)(ktile + ((size_t)jj * 32 + tb16) * 768 + h) = r;
    }
}

// ---------------- phase 1: LDS-staged GEMM (128x256 tile) + sum-softmax partials ------
// grid: x = st*2 + tb (8), y = j (16), z = i (8); 512 threads = 8 waves of 64x64.
// Identical to the proven baseline EXCEPT (when elide): waves whose 64x64 output block
// is entirely in the far band (|sB - tB| >= 4, min |s-t| = 193) skip their frag reads
// + MFMAs (acc stays 0), and K-tiles needed by no resident wave are not staged.
__global__ __launch_bounds__(512, 4)
void li_part(const _Float16* __restrict__ Qt, const _Float16* __restrict__ Kt,
             const float* __restrict__ alpha_p, const int* __restrict__ kmask,
             float* __restrict__ Pbuf, int elide)
{
    const int st = blockIdx.x >> 1;   // s tile (0..3), 128 rows
    const int tb = blockIdx.x & 1;    // t half (0..1), 256 cols
    const int j  = blockIdx.y;
    const int i  = blockIdx.z;

    const int tid  = threadIdx.x;
    const int lane = tid & 63;
    const int wave = tid >> 6;        // 0..7
    const int quad = lane >> 4;
    const int l16  = lane & 15;
    const int wr   = wave >> 2;       // row half (0/1): rows wr*64..+63
    const int wc   = wave & 3;        // col quarter (0..3): cols wc*64..+63

    // double-buffered staging: 24 tiles (8 Q + 16 K) x 512 halves per buffer
    __shared__ _Float16 Sbuf[2][24 * 512];
    __shared__ float lred[4][128], nred[4][128];

    const float araw  = *alpha_p;
    const float alpha = araw >= 0.f ? araw : 0.01f * araw;   // leaky_relu
    const bool skip_en = (elide != 0) && SKIP_OK(alpha);

    // this wave's 64-row / 64-col block position in 64-units
    const int sB = st * 2 + wr;       // 0..7
    const int tB = tb * 4 + wc;       // 0..7
    const int dB = sB - tB;
    const bool wskip = skip_en && (dB >= 4 || dB <= -4);

    const int qbase = i * 32 + st * 8;        // Q row-block index
    const int kbase = j * 32 + tb * 16;       // K row-block index

    // staging assignment: this wave stages tiles wave*3 .. wave*3+2
    const _Float16* gsrc[3];
    _Float16*       ldst0[3];
    bool            need[3];
#pragma unroll
    for (int q = 0; q < 3; ++q) {
        int t   = wave * 3 + q;
        int rbg = (t < 8) ? (qbase + t) : (kbase + (t - 8));
        const _Float16* base = (t < 8) ? Qt : Kt;
        gsrc[q]  = base + (size_t)rbg * NKB * 512 + (size_t)lane * 8;
        ldst0[q] = &Sbuf[0][t * 512];
        if (t < 8) need[q] = true;
        else {
            int tBq = tb * 4 + ((t - 8) >> 2);
            int d0 = st * 2 - tBq, d1 = st * 2 + 1 - tBq;
            bool near = (d0 <= 3 && d0 >= -3) || (d1 <= 3 && d1 >= -3);
            need[q] = !skip_en || near;
        }
    }

    floatx4 acc[4][4];
#pragma unroll
    for (int rt = 0; rt < 4; ++rt)
#pragma unroll
        for (int ct = 0; ct < 4; ++ct)
            acc[rt][ct] = (floatx4){0.f, 0.f, 0.f, 0.f};

    // stage kb=0 into buffer 0
#pragma unroll
    for (int q = 0; q < 3; ++q)
        if (need[q]) async_tile16(gsrc[q], ldst0[q]);

    for (int kb = 0; kb < NKB; ++kb) {
        const int b = kb & 1;
        __syncthreads();   // drains own staging (vmcnt) + fences prior reads of buf b^1
        if (kb + 1 < NKB) {
#pragma unroll
            for (int q = 0; q < 3; ++q)
                if (need[q]) async_tile16(gsrc[q] + (size_t)(kb + 1) * 512, ldst0[q] + (b ^ 1) * 24 * 512);
        }
        if (!wskip) {
            const _Float16* Qs = &Sbuf[b][0];
            const _Float16* Ks = &Sbuf[b][8 * 512];
            half8 af[4], bf[4];
#pragma unroll
            for (int rt = 0; rt < 4; ++rt)
                af[rt] = *(const half8*)(Qs + (wr * 4 + rt) * 512 + lane * 8);
#pragma unroll
            for (int ct = 0; ct < 4; ++ct)
                bf[ct] = *(const half8*)(Ks + (wc * 4 + ct) * 512 + lane * 8);
#pragma unroll
            for (int rt = 0; rt < 4; ++rt)
#pragma unroll
                for (int ct = 0; ct < 4; ++ct)
                    acc[rt][ct] = __builtin_amdgcn_mfma_f32_16x16x32_f16(af[rt], bf[ct], acc[rt][ct], 0, 0, 0);
        }
    }

    // ---- epilogue: sum-softmax partials (logits in [-1,1] -> no max needed) ----
    // For skipped waves acc==0: e = kmv ? expf(0) = 1 : 0 -> ps exact, ns contributes 0
    // (restored in li_reduce via the rank-1 far correction).
    const int* km = kmask + j * SEQ_ + tb * 256;
    int kmv[4]; float tgf[4];
#pragma unroll
    for (int ct = 0; ct < 4; ++ct) {
        int t_loc = wc * 64 + ct * 16 + l16;
        kmv[ct] = km[t_loc];
        tgf[ct] = (float)(tb * 256 + t_loc);
    }
#pragma unroll
    for (int rt = 0; rt < 4; ++rt) {
#pragma unroll
        for (int r = 0; r < 4; ++r) {
            float sgf = (float)(st * 128 + wr * 64 + rt * 16 + quad * 4 + r);
            float ps = 0.f, ns = 0.f;
#pragma unroll
            for (int ct = 0; ct < 4; ++ct) {
                float cv = acc[rt][ct][r];
                float e  = kmv[ct] ? __expf(cv * __expf(-alpha * fabsf(sgf - tgf[ct]))) : 0.f;
                ps += e;
                ns += e * cv;
            }
#pragma unroll
            for (int msk = 1; msk < 16; msk <<= 1) {
                ps += __shfl_xor(ps, msk, 64);
                ns += __shfl_xor(ns, msk, 64);
            }
            if (l16 == 0) {
                int rloc = wr * 64 + rt * 16 + quad * 4 + r;
                lred[wc][rloc] = ps;
                nred[wc][rloc] = ns;
            }
        }
    }
    __syncthreads();

    // merge 4 col-quarters; one (l,n) per row per t-half
    if (tid < 128) {
        float l = lred[0][tid] + lred[1][tid] + lred[2][tid] + lred[3][tid];
        float n = nred[0][tid] + nred[1][tid] + nred[2][tid] + nred[3][tid];
        size_t base = (((size_t)(i * KB_ + j) * SEQ_) + st * 128 + tid) * 4 + tb * 2;
        Pbuf[base]     = l;
        Pbuf[base + 1] = n;
    }
}

// ---------------- phase 2: far correction + merge t-halves + reduce over s ------------
// One block per (i,j), 512 threads = 8 waves, three parallel phases (2 barriers):
//   P1: G[sB][768] = sum_{t16: |t16>>2 - sB| >= 4} ktile[j][t16]  (coalesced float4)
//   P2: wave w owns sB=w: nfar[s] = qn[s] . G[sB]  (half8 Qt loads, LDS-broadcast G)
//   P3: merge Pbuf halves + nfar, qmask, reduce over s.
__global__ __launch_bounds__(512)
void li_reduce(const float* __restrict__ Pbuf, const int* __restrict__ qmask,
               const _Float16* __restrict__ Qt, const float* __restrict__ ktile,
               const float* __restrict__ alpha_p, float* __restrict__ out, int elide)
{
    const int ij = blockIdx.x;
    const int i  = ij >> 4;           // KB_ == 16
    const int j  = ij & 15;
    const int tid  = threadIdx.x;
    const int lane = tid & 63;
    const int wave = tid >> 6;        // 0..7

    __shared__ float Gs[8][768];
    __shared__ float nfar[512];
    __shared__ float red[8];

    const float araw  = *alpha_p;
    const float alpha = araw >= 0.f ? araw : 0.01f * araw;   // leaky_relu
    const bool skip_en = (elide != 0) && SKIP_OK(alpha);

    if (skip_en) {
        // ---- P1: far-sums, all 512 threads. thread (sB=tid>>6, t=tid&63) owns
        // float4 chunks c*64+t (c=0..2) of G[sB]; reads are lane-coalesced.
        {
            const int sB = wave;
            const int t  = lane;
            const float4* kt4 = (const float4*)(ktile + (size_t)j * 32 * 768);
#pragma unroll
            for (int c = 0; c < 3; ++c) {
                int idx4 = c * 64 + t;               // 0..191
                float4 a = {0.f, 0.f, 0.f, 0.f};
                for (int t16 = 0; t16 < 32; ++t16) {
                    int d = (t16 >> 2) - sB;
                    if (d >= 4 || d <= -4) {
                        float4 v = kt4[t16 * 192 + idx4];
                        a.x += v.x; a.y += v.y; a.z += v.z; a.w += v.w;
                    }
                }
                *(float4*)(&Gs[sB][idx4 * 4]) = a;
            }
        }
        __syncthreads();

        // ---- P2: wave w owns sB=w (64 s-rows = 4 rowblocks), no barriers.
        {
            const int sB = wave;
            const int kq = (lane >> 4) * 8;
#pragma unroll
            for (int rb = 0; rb < 4; ++rb) {
                const _Float16* qb = Qt + ((size_t)i * 32 + sB * 4 + rb) * (NKB * 512)
                                        + (size_t)lane * 8;
                float p = 0.f;
#pragma unroll 4
                for (int kb = 0; kb < NKB; ++kb) {
                    half8 q8 = *(const half8*)(qb + kb * 512);
                    const float* w8 = &Gs[sB][kb * 32 + kq];
#pragma unroll
                    for (int m = 0; m < 8; ++m) p += (float)q8[m] * w8[m];
                }
                p += __shfl_xor(p, 16, 64);   // sum the 4 lanes sharing a row
                p += __shfl_xor(p, 32, 64);
                if (lane < 16) nfar[sB * 64 + rb * 16 + lane] = p;
            }
        }
    } else {
        nfar[tid] = 0.f;
    }
    __syncthreads();

    // ---- P3: merge + reduce (512 threads, one s each)
    float sum;
    {
        int s = tid;
        float4 a = *(const float4*)(Pbuf + ((size_t)ij * SEQ_ + s) * 4);
        float l = a.x + a.z;
        float n = a.y + a.w + nfar[s];
        float sc = (l > 0.f) ? n / l : 0.f;
        if (qmask[i * SEQ_ + s] == 0) sc = 0.f;
        sum = sc;
    }
#pragma unroll
    for (int m = 1; m < 64; m <<= 1) sum += __shfl_xor(sum, m, 64);
    if (lane == 0) red[wave] = sum;
    __syncthreads();
    if (tid == 0) {
        float r = 0.f;
#pragma unroll
        for (int w = 0; w < 8; ++w) r += red[w];
        out[ij] = r;
    }
}

extern "C" void kernel_launch(void* const* d_in, const int* in_sizes, int n_in,
                              void* d_out, int out_size, void* d_ws, size_t ws_size,
                              hipStream_t stream)
{
    const float* Q       = (const float*)d_in[0];
    const float* K       = (const float*)d_in[1];
    const float* alpha_p = (const float*)d_in[2];
    const int*   qmask   = (const int*)d_in[3];
    const int*   kmask   = (const int*)d_in[4];
    float*       out     = (float*)d_out;

    char* ws = (char*)d_ws;
    _Float16* Qt    = (_Float16*)ws;
    _Float16* Kt    = (_Float16*)(ws + (size_t)B_ * SEQ_ * HID_ * 2);
    float*    Pbuf  = (float*)   (ws + (size_t)(B_ + KB_) * SEQ_ * HID_ * 2);
    float*    ktile = (float*)   (ws + WS_BASE);

    // band-elision needs +1.5 MB workspace past the baseline layout; gate on ws_size
    const int elide = (ws_size >= WS_BASE + WS_KTILE) ? 1 : 0;

    prep_tile<<<QRB + KRB, 256, 0, stream>>>(Q, K, kmask, Qt, Kt, ktile, elide);

    dim3 grid(8, KB_, B_);   // (st*2+tb, j, i)
    li_part<<<grid, 512, 0, stream>>>(Qt, Kt, alpha_p, kmask, Pbuf, elide);

    li_reduce<<<B_ * KB_, 512, 0, stream>>>(Pbuf, qmask, Qt, ktile, alpha_p, out, elide);
}

// Round 9
// 145.466 us; speedup vs baseline: 1.4566x; 1.1692x over previous
//
#include <hip/hip_runtime.h>
#include <stdint.h>

#define B_   8
#define KB_  16
#define SEQ_ 512
#define HID_ 768

#define NKB  (HID_ / 32)         // 24 k-blocks (32 halves each) per row
#define QRB  (B_  * SEQ_ / 16)   // 256 Q row-blocks of 16 rows
#define KRB  (KB_ * SEQ_ / 16)   // 512 K row-blocks

typedef __attribute__((ext_vector_type(4))) _Float16 half4;
typedef __attribute__((ext_vector_type(8))) _Float16 half8;
typedef __attribute__((ext_vector_type(4))) float    floatx4;

#define GLOBAL_AS __attribute__((address_space(1)))
#define LDS_AS    __attribute__((address_space(3)))

// async 16B/lane global->LDS copy: LDS dest = base + lane*16 (wave-uniform base)
static __device__ __forceinline__ void async_tile16(const _Float16* g, _Float16* l)
{
    __builtin_amdgcn_global_load_lds((const GLOBAL_AS uint32_t*)g,
                                     (LDS_AS uint32_t*)l, 16, 0, 0);
}

// ---------------- prepass: L2-normalize rows -> fp16 in MFMA-fragment-tiled layout ----
// Tile = 16 rows x 32 k = 1KB, lane-major: element(row,k) at lane = row | ((k>>3)<<4),
// idx = k&7. One 256-thread block per 16-row block.
#define LP 776   // LDS row stride in halves

__global__ __launch_bounds__(256)
void prep_tile(const float* __restrict__ Q, const float* __restrict__ K,
               _Float16* __restrict__ Qt, _Float16* __restrict__ Kt)
{
    const int rb = blockIdx.x;   // 0..767
    const float* src;
    _Float16*    dst;
    if (rb < QRB) { src = Q + (size_t)rb * 16 * HID_;          dst = Qt + (size_t)rb * NKB * 512; }
    else          { src = K + (size_t)(rb - QRB) * 16 * HID_;  dst = Kt + (size_t)(rb - QRB) * NKB * 512; }

    __shared__ _Float16 Ls[16 * LP];
    const int wave = threadIdx.x >> 6;
    const int lane = threadIdx.x & 63;

#pragma unroll
    for (int rr = 0; rr < 4; ++rr) {
        int row = wave * 4 + rr;
        const float* s = src + (size_t)row * HID_;
        float4 v[3];
        float ss = 0.f;
#pragma unroll
        for (int it = 0; it < 3; ++it) {
            v[it] = *(const float4*)(s + lane * 4 + it * 256);
            ss += v[it].x * v[it].x + v[it].y * v[it].y + v[it].z * v[it].z + v[it].w * v[it].w;
        }
#pragma unroll
        for (int m = 1; m < 64; m <<= 1) ss += __shfl_xor(ss, m, 64);
        float sc = 1.0f / fmaxf(sqrtf(ss), 1e-12f);
#pragma unroll
        for (int it = 0; it < 3; ++it) {
            half4 h = { (_Float16)(v[it].x * sc), (_Float16)(v[it].y * sc),
                        (_Float16)(v[it].z * sc), (_Float16)(v[it].w * sc) };
            *(half4*)(Ls + row * LP + lane * 4 + it * 256) = h;
        }
    }
    __syncthreads();

#pragma unroll
    for (int rep = 0; rep < 6; ++rep) {
        int slot = rep * 256 + threadIdx.x;      // 0..1535 = 24 tiles x 64 lanes
        int kb   = slot >> 6;
        int ln   = slot & 63;
        int row  = ln & 15;
        int ko   = kb * 32 + (ln >> 4) * 8;
        half8 h = *(const half8*)(Ls + row * LP + ko);
        *(half8*)(dst + (size_t)kb * 512 + (size_t)ln * 8) = h;
    }
}

// ---------------- phase 1: LDS-staged GEMM (128x256 tile) + sum-softmax partials ------
// 1-D grid of 1024, XCD-aware swizzle: hw block F -> c = F&7 (XCD under round-robin
// dispatch), m = F>>3; work group g = c + 8*(m>>3) (so all 8 st/tb blocks of one (i,j)
// land consecutively on ONE XCD -> its 4MB L2 holds that (i,j)'s Q/K panels; staging
// hits L2 instead of L3), r = m&7. 512 threads = 8 waves of 64x64.
__global__ __launch_bounds__(512, 4)
void li_part(const _Float16* __restrict__ Qt, const _Float16* __restrict__ Kt,
             const float* __restrict__ alpha_p, const int* __restrict__ kmask,
             float* __restrict__ Pbuf)
{
    const int F = blockIdx.x;         // 0..1023
    const int c = F & 7;              // XCD id under round-robin dispatch
    const int m = F >> 3;
    const int g = c + ((m >> 3) << 3);// (i,j) group 0..127, g % 8 == c
    const int r = m & 7;              // st*2 + tb
    const int st = r >> 1;            // s tile (0..3), 128 rows
    const int tb = r & 1;             // t half (0..1), 256 cols
    const int j  = g & 15;
    const int i  = g >> 4;

    const int tid  = threadIdx.x;
    const int lane = tid & 63;
    const int wave = tid >> 6;        // 0..7
    const int quad = lane >> 4;
    const int l16  = lane & 15;
    const int wr   = wave >> 2;       // row half (0/1): rows wr*64..+63
    const int wc   = wave & 3;        // col quarter (0..3): cols wc*64..+63

    // double-buffered staging: 24 tiles (8 Q + 16 K) x 512 halves per buffer
    __shared__ _Float16 Sbuf[2][24 * 512];
    __shared__ float lred[4][128], nred[4][128];

    const float araw  = *alpha_p;
    const float alpha = araw >= 0.f ? araw : 0.01f * araw;   // leaky_relu

    const int qbase = i * 32 + st * 8;        // Q row-block index
    const int kbase = j * 32 + tb * 16;       // K row-block index

    // staging assignment: this wave stages tiles wave*3 .. wave*3+2
    const _Float16* gsrc[3];
    _Float16*       ldst0[3];
#pragma unroll
    for (int q = 0; q < 3; ++q) {
        int t   = wave * 3 + q;
        int rbg = (t < 8) ? (qbase + t) : (kbase + (t - 8));
        const _Float16* base = (t < 8) ? Qt : Kt;
        gsrc[q]  = base + (size_t)rbg * NKB * 512 + (size_t)lane * 8;
        ldst0[q] = &Sbuf[0][t * 512];
    }

    floatx4 acc[4][4];
#pragma unroll
    for (int rt = 0; rt < 4; ++rt)
#pragma unroll
        for (int ct = 0; ct < 4; ++ct)
            acc[rt][ct] = (floatx4){0.f, 0.f, 0.f, 0.f};

    // stage kb=0 into buffer 0
#pragma unroll
    for (int q = 0; q < 3; ++q)
        async_tile16(gsrc[q], ldst0[q]);

    for (int kb = 0; kb < NKB; ++kb) {
        const int b = kb & 1;
        __syncthreads();   // drains own staging (vmcnt) + fences prior reads of buf b^1
        if (kb + 1 < NKB) {
#pragma unroll
            for (int q = 0; q < 3; ++q)
                async_tile16(gsrc[q] + (size_t)(kb + 1) * 512, ldst0[q] + (b ^ 1) * 24 * 512);
        }
        const _Float16* Qs = &Sbuf[b][0];
        const _Float16* Ks = &Sbuf[b][8 * 512];
        half8 af[4], bf[4];
#pragma unroll
        for (int rt = 0; rt < 4; ++rt)
            af[rt] = *(const half8*)(Qs + (wr * 4 + rt) * 512 + lane * 8);
#pragma unroll
        for (int ct = 0; ct < 4; ++ct)
            bf[ct] = *(const half8*)(Ks + (wc * 4 + ct) * 512 + lane * 8);
#pragma unroll
        for (int rt = 0; rt < 4; ++rt)
#pragma unroll
            for (int ct = 0; ct < 4; ++ct)
                acc[rt][ct] = __builtin_amdgcn_mfma_f32_16x16x32_f16(af[rt], bf[ct], acc[rt][ct], 0, 0, 0);
    }

    // ---- epilogue: sum-softmax partials (logits in [-1,1] -> no max needed) ----
    const int* km = kmask + j * SEQ_ + tb * 256;
    int kmv[4]; float tgf[4];
#pragma unroll
    for (int ct = 0; ct < 4; ++ct) {
        int t_loc = wc * 64 + ct * 16 + l16;
        kmv[ct] = km[t_loc];
        tgf[ct] = (float)(tb * 256 + t_loc);
    }
#pragma unroll
    for (int rt = 0; rt < 4; ++rt) {
#pragma unroll
        for (int r2 = 0; r2 < 4; ++r2) {
            float sgf = (float)(st * 128 + wr * 64 + rt * 16 + quad * 4 + r2);
            float ps = 0.f, ns = 0.f;
#pragma unroll
            for (int ct = 0; ct < 4; ++ct) {
                float cv = acc[rt][ct][r2];
                float e  = kmv[ct] ? __expf(cv * __expf(-alpha * fabsf(sgf - tgf[ct]))) : 0.f;
                ps += e;
                ns += e * cv;
            }
#pragma unroll
            for (int msk = 1; msk < 16; msk <<= 1) {
                ps += __shfl_xor(ps, msk, 64);
                ns += __shfl_xor(ns, msk, 64);
            }
            if (l16 == 0) {
                int rloc = wr * 64 + rt * 16 + quad * 4 + r2;
                lred[wc][rloc] = ps;
                nred[wc][rloc] = ns;
            }
        }
    }
    __syncthreads();

    // merge 4 col-quarters; one (l,n) per row per t-half
    if (tid < 128) {
        float l = lred[0][tid] + lred[1][tid] + lred[2][tid] + lred[3][tid];
        float n = nred[0][tid] + nred[1][tid] + nred[2][tid] + nred[3][tid];
        size_t base = (((size_t)(i * KB_ + j) * SEQ_) + st * 128 + tid) * 4 + tb * 2;
        Pbuf[base]     = l;
        Pbuf[base + 1] = n;
    }
}

// ---------------- phase 2: merge t-halves, apply q_mask, reduce over s ----------------
__global__ __launch_bounds__(256)
void li_reduce(const float* __restrict__ Pbuf, const int* __restrict__ qmask,
               float* __restrict__ out)
{
    const int ij = blockIdx.x;
    const int i  = ij >> 4;           // KB_ == 16
    const int tid = threadIdx.x;
    __shared__ float red[4];

    float sum = 0.f;
#pragma unroll
    for (int rep = 0; rep < 2; ++rep) {
        int s = tid + rep * 256;
        float4 a = *(const float4*)(Pbuf + ((size_t)ij * SEQ_ + s) * 4);
        float l = a.x + a.z;
        float n = a.y + a.w;
        float sc = (l > 0.f) ? n / l : 0.f;
        if (qmask[i * SEQ_ + s] == 0) sc = 0.f;
        sum += sc;
    }
#pragma unroll
    for (int m = 1; m < 64; m <<= 1) sum += __shfl_xor(sum, m, 64);
    if ((tid & 63) == 0) red[tid >> 6] = sum;
    __syncthreads();
    if (tid == 0) out[ij] = red[0] + red[1] + red[2] + red[3];
}

extern "C" void kernel_launch(void* const* d_in, const int* in_sizes, int n_in,
                              void* d_out, int out_size, void* d_ws, size_t ws_size,
                              hipStream_t stream)
{
    const float* Q       = (const float*)d_in[0];
    const float* K       = (const float*)d_in[1];
    const float* alpha_p = (const float*)d_in[2];
    const int*   qmask   = (const int*)d_in[3];
    const int*   kmask   = (const int*)d_in[4];
    float*       out     = (float*)d_out;

    char* ws = (char*)d_ws;
    _Float16* Qt   = (_Float16*)ws;
    _Float16* Kt   = (_Float16*)(ws + (size_t)B_ * SEQ_ * HID_ * 2);
    float*    Pbuf = (float*)   (ws + (size_t)(B_ + KB_) * SEQ_ * HID_ * 2);

    prep_tile<<<QRB + KRB, 256, 0, stream>>>(Q, K, Qt, Kt);

    li_part<<<1024, 512, 0, stream>>>(Qt, Kt, alpha_p, kmask, Pbuf);

    li_reduce<<<B_ * KB_, 256, 0, stream>>>(Pbuf, qmask, out);
}